// Round 1
// baseline (23296.240 us; speedup 1.0000x reference)
//
#include <hip/hip_runtime.h>
#include <math.h>

#define STRIDE 66            // 64 positions + 2 zero-pad columns (col 0 and 65)
#define EPS_OH 0.999f

__device__ __forceinline__ float waveSum(float v) {
#pragma unroll
  for (int off = 32; off; off >>= 1) v += __shfl_xor(v, off);
  return v;
}
__device__ __forceinline__ float waveMax(float v) {
#pragma unroll
  for (int off = 32; off; off >>= 1) v = fmaxf(v, __shfl_xor(v, off));
  return v;
}
__device__ __forceinline__ float leaky(float x) { return x >= 0.f ? x : 0.1f * x; }

// ---------------- question-side conv block: y = leaky(conv(x)+b) + x, x:(32,300)
__global__ __launch_bounds__(256) void qconv_kernel(
    const float* __restrict__ x, const float* __restrict__ W,
    const float* __restrict__ b, float* __restrict__ y)
{
  int idx = blockIdx.x * 256 + threadIdx.x;
  if (idx >= 32 * 300) return;
  int o = idx % 300, l = idx / 300;
  const float* Wo = W + o * 900;
  float acc = b[o];
#pragma unroll 4
  for (int i = 0; i < 300; ++i) {
    float x1 = x[l * 300 + i];
    float x0 = (l >= 1) ? x[(l - 1) * 300 + i] : 0.f;
    float x2 = (l <= 30) ? x[(l + 1) * 300 + i] : 0.f;
    acc += Wo[i * 3] * x0 + Wo[i * 3 + 1] * x1 + Wo[i * 3 + 2] * x2;
  }
  y[l * 300 + o] = leaky(acc) + x[l * 300 + o];
}

// ---------------- q_weights softmax + normalized qn / qcn
__global__ __launch_bounds__(256) void qfinish_kernel(
    const float* __restrict__ qemb, const float* __restrict__ qctx,
    const float* __restrict__ qidf, const float* __restrict__ qww,
    const float* __restrict__ qwb,
    float* __restrict__ qn, float* __restrict__ qcn, float* __restrict__ qwv)
{
  __shared__ float nq[32], nqc[32], lg[32];
  int tid = threadIdx.x, lane = tid & 63, w = tid >> 6;
  int r = w * 8 + (lane >> 3), sub = lane & 7;
  float sq = 0.f, sqc = 0.f, dt = 0.f;
  for (int i = sub; i < 300; i += 8) {
    float a = qemb[r * 300 + i]; sq  += a * a;
    float c = qctx[r * 300 + i]; sqc += c * c;
    dt += c * qww[i];
  }
#pragma unroll
  for (int off = 4; off; off >>= 1) {
    sq  += __shfl_xor(sq, off);
    sqc += __shfl_xor(sqc, off);
    dt  += __shfl_xor(dt, off);
  }
  if (sub == 0) {
    nq[r] = sq; nqc[r] = sqc;
    lg[r] = dt + qidf[r] * qww[300] + qwb[0];
  }
  __syncthreads();
  if (w == 0) {
    float L = (lane < 32) ? lg[lane] : -1e30f;
    float m = L;
#pragma unroll
    for (int off = 32; off; off >>= 1) m = fmaxf(m, __shfl_xor(m, off));
    float e = (lane < 32) ? expf(L - m) : 0.f;
    float ssum = e;
#pragma unroll
    for (int off = 32; off; off >>= 1) ssum += __shfl_xor(ssum, off);
    if (lane < 32) qwv[lane] = e / ssum;
  }
  __syncthreads();
  for (int idx = tid; idx < 9600; idx += 256) {
    int rr = idx / 300;
    qn[idx]  = qemb[idx] / sqrtf(nq[rr]);
    qcn[idx] = qctx[idx] / sqrtf(nqc[rr]);
  }
}

// ---------------- fused per-sentence kernel helpers
__device__ __forceinline__ void row_norms(const float* src, float* pn, float* snorm,
                                          int w, int lane, int tid)
{
  float p = 0.f;
  for (int i = w * 75; i < (w + 1) * 75; ++i) {
    float v = src[i * STRIDE + 1 + lane];
    p += v * v;
  }
  pn[w * 64 + lane] = p;
  __syncthreads();
  if (tid < 64)
    snorm[tid] = 1.f / sqrtf(pn[tid] + pn[64 + tid] + pn[128 + tid] + pn[192 + tid]);
  __syncthreads();
}

// sim pooling: wave w handles q = w*8 .. w*8+7; 64 lanes = 64 positions
__device__ __forceinline__ void sim_pool_phase(const float* src, const float* __restrict__ qmat,
                                               const float* snorm, float (*feat)[9],
                                               int w, int lane, int foff, bool do_oh)
{
  float invn = snorm[lane];
  for (int j = 0; j < 8; ++j) {
    int q = __builtin_amdgcn_readfirstlane(w * 8 + j);
    const float* qv = qmat + q * 300;
    float dot = 0.f;
#pragma unroll 4
    for (int i = 0; i < 300; ++i) dot += qv[i] * src[i * STRIDE + 1 + lane];
    float sim = dot * invn;
    float ssum = waveSum(sim);
    float vv = sim, tmax = 0.f, t5 = 0.f;
#pragma unroll
    for (int it = 0; it < 5; ++it) {
      float m = waveMax(vv);
      if (it == 0) tmax = m;
      t5 += m;
      unsigned long long bb = __ballot(vv == m);
      if (lane == (int)__builtin_ctzll(bb)) vv = -3e38f;
    }
    if (do_oh) {
      int c = __popcll(__ballot(sim > EPS_OH));
      if (lane == 0) {
        feat[q][0] = (c > 0) ? 1.f : 0.f;
        feat[q][1] = (c < 5 ? (float)c : 5.f) * 0.2f;
        feat[q][2] = (float)c * (1.f / 64.f);
      }
    }
    if (lane == 0) {
      feat[q][foff + 0] = tmax;
      feat[q][foff + 1] = t5 * 0.2f;
      feat[q][foff + 2] = ssum * (1.f / 64.f);
    }
  }
}

// residual conv block in LDS: dst[o][l] = leaky(sum_{i,k} W[o,i,k]*src[i][l+k-1] + b[o]) + src[o][l]
__device__ __forceinline__ void conv_block_lds(const float* src, float* dst,
                                               const float* __restrict__ W,
                                               const float* __restrict__ bias,
                                               int w, int lane)
{
  for (int c = 0; c < 15; ++c) {
    int o0 = __builtin_amdgcn_readfirstlane(w * 75 + c * 5);
    const float* W0 = W + o0 * 900;
    float a0 = 0.f, a1 = 0.f, a2 = 0.f, a3 = 0.f, a4 = 0.f;
    for (int i = 0; i < 300; ++i) {
      float x0 = src[i * STRIDE + lane];       // position lane-1 (pad col 0 = 0)
      float x1 = src[i * STRIDE + lane + 1];   // position lane
      float x2 = src[i * STRIDE + lane + 2];   // position lane+1 (pad col 65 = 0)
      const float* Wi = W0 + i * 3;
      a0 += Wi[0]    * x0 + Wi[1]    * x1 + Wi[2]    * x2;
      a1 += Wi[900]  * x0 + Wi[901]  * x1 + Wi[902]  * x2;
      a2 += Wi[1800] * x0 + Wi[1801] * x1 + Wi[1802] * x2;
      a3 += Wi[2700] * x0 + Wi[2701] * x1 + Wi[2702] * x2;
      a4 += Wi[3600] * x0 + Wi[3601] * x1 + Wi[3602] * x2;
    }
    float acc[5] = {a0, a1, a2, a3, a4};
#pragma unroll
    for (int j = 0; j < 5; ++j) {
      int o = o0 + j;
      float v = leaky(acc[j] + bias[o]);
      dst[o * STRIDE + 1 + lane] = v + src[o * STRIDE + 1 + lane];
    }
  }
}

__global__ __launch_bounds__(256) void sent_kernel(
    const float* __restrict__ doc, const float* __restrict__ qn,
    const float* __restrict__ qcn, const float* __restrict__ qwv,
    const float* __restrict__ gaf,
    const float* __restrict__ W1, const float* __restrict__ b1,
    const float* __restrict__ W2, const float* __restrict__ b2,
    const float* __restrict__ m1w, const float* __restrict__ m1b,
    const float* __restrict__ m2w, const float* __restrict__ m2b,
    const float* __restrict__ ow, float* __restrict__ out)
{
  __shared__ float A[300 * STRIDE];
  __shared__ float B[300 * STRIDE];
  __shared__ float pn[256];
  __shared__ float snorm[64];
  __shared__ float feat[32][9];

  int tid = threadIdx.x, lane = tid & 63, w = tid >> 6;
  int s = blockIdx.x;
  const float* x = doc + (size_t)s * 19200;

  // Phase 0: load x -> LDS channel-major, zero pads
  for (int idx = tid; idx < 19200; idx += 256) {
    int l = idx / 300, i = idx - l * 300;
    A[i * STRIDE + 1 + l] = x[idx];
  }
  for (int i = tid; i < 300; i += 256) {
    A[i * STRIDE] = 0.f; A[i * STRIDE + 65] = 0.f;
    B[i * STRIDE] = 0.f; B[i * STRIDE + 65] = 0.f;
  }
  __syncthreads();

  // Phase 1: sim_insens + sim_oh pooling on raw x
  row_norms(A, pn, snorm, w, lane, tid);
  sim_pool_phase(A, qn, snorm, feat, w, lane, 3, true);
  __syncthreads();

  // Phase 2: conv1  A -> B
  conv_block_lds(A, B, W1, b1, w, lane);
  __syncthreads();

  // Phase 3: conv2  B -> A  (x is dead now)
  conv_block_lds(B, A, W2, b2, w, lane);
  __syncthreads();

  // Phase 4: sim_sens pooling on sent_ctx (in A)
  row_norms(A, pn, snorm, w, lane, tid);
  sim_pool_phase(A, qcn, snorm, feat, w, lane, 6, false);
  __syncthreads();

  // Phase 5: MLP + weighted emit + final sigmoid (wave 0)
  if (w == 0) {
    float val = 0.f;
    if (lane < 32) {
      int q = lane;
      float o8 = m2b[0];
#pragma unroll
      for (int j = 0; j < 8; ++j) {
        float a = m1b[j];
#pragma unroll
        for (int f = 0; f < 9; ++f) a += m1w[j * 9 + f] * feat[q][f];
        a = leaky(a);
        o8 += m2w[j] * a;
      }
      val = o8 * qwv[q];
    }
    float tot = waveSum(val);
    if (lane == 0) {
      float emit = tot * (1.f / 32.f);
      float z = gaf[s * 3 + 0] * ow[0] + gaf[s * 3 + 1] * ow[1] +
                gaf[s * 3 + 2] * ow[2] + emit * ow[3];
      out[s] = 1.f / (1.f + expf(-z));
    }
  }
}

extern "C" void kernel_launch(void* const* d_in, const int* in_sizes, int n_in,
                              void* d_out, int out_size, void* d_ws, size_t ws_size,
                              hipStream_t stream)
{
  const float* doc  = (const float*)d_in[0];
  const float* qemb = (const float*)d_in[1];
  const float* qidf = (const float*)d_in[2];
  const float* gaf  = (const float*)d_in[3];
  const float* W1   = (const float*)d_in[4];
  const float* b1   = (const float*)d_in[5];
  const float* W2   = (const float*)d_in[6];
  const float* b2   = (const float*)d_in[7];
  const float* qww  = (const float*)d_in[8];
  const float* qwb  = (const float*)d_in[9];
  const float* m1w  = (const float*)d_in[10];
  const float* m1b  = (const float*)d_in[11];
  const float* m2w  = (const float*)d_in[12];
  const float* m2b  = (const float*)d_in[13];
  const float* ow   = (const float*)d_in[14];
  float* out = (float*)d_out;

  float* ws   = (float*)d_ws;
  float* qc1  = ws;            // 9600
  float* qctx = ws + 9600;     // 9600
  float* qn   = ws + 19200;    // 9600
  float* qcn  = ws + 28800;    // 9600
  float* qwv  = ws + 38400;    // 32

  qconv_kernel<<<38, 256, 0, stream>>>(qemb, W1, b1, qc1);
  qconv_kernel<<<38, 256, 0, stream>>>(qc1, W2, b2, qctx);
  qfinish_kernel<<<1, 256, 0, stream>>>(qemb, qctx, qidf, qww, qwb, qn, qcn, qwv);
  sent_kernel<<<4096, 256, 0, stream>>>(doc, qn, qcn, qwv, gaf,
                                        W1, b1, W2, b2,
                                        m1w, m1b, m2w, m2b, ow, out);
}

// Round 2
// 827.425 us; speedup vs baseline: 28.1551x; 28.1551x over previous
//
#include <hip/hip_runtime.h>
#include <math.h>

typedef __attribute__((ext_vector_type(8))) short short8;
typedef __attribute__((ext_vector_type(4))) short short4_t;
typedef __attribute__((ext_vector_type(4))) float f32x4;

#define XSTRIDE 328          // bf16 elems per LDS row; 656B = 41*16 (b128-aligned), 164 dwords %32=4 -> 2-way banks (free)
#define NROWS   66           // rows = positions -1..64 (row = l+1), rows 0,65 = zero pad
#define EPS_OH  0.999f

__device__ __forceinline__ float waveSum(float v) {
#pragma unroll
  for (int off = 32; off; off >>= 1) v += __shfl_xor(v, off);
  return v;
}
__device__ __forceinline__ float waveMax(float v) {
#pragma unroll
  for (int off = 32; off; off >>= 1) v = fmaxf(v, __shfl_xor(v, off));
  return v;
}
__device__ __forceinline__ float leaky(float x) { return fmaxf(x, 0.1f * x); }

// bf16 <-> f32 via bit ops (RNE round)
__device__ __forceinline__ short f2b(float f) {
  unsigned u = __float_as_uint(f);
  unsigned r = (u + 0x7FFFu + ((u >> 16) & 1u)) >> 16;
  return (short)r;
}
__device__ __forceinline__ float b2f(short h) {
  return __uint_as_float(((unsigned)(unsigned short)h) << 16);
}

// ---------------- question-side conv block (fp32, tiny) ----------------
__global__ __launch_bounds__(256) void qconv_kernel(
    const float* __restrict__ x, const float* __restrict__ W,
    const float* __restrict__ b, float* __restrict__ y)
{
  int idx = blockIdx.x * 256 + threadIdx.x;
  if (idx >= 32 * 300) return;
  int o = idx % 300, l = idx / 300;
  const float* Wo = W + o * 900;
  float acc = b[o];
#pragma unroll 4
  for (int i = 0; i < 300; ++i) {
    float x1 = x[l * 300 + i];
    float x0 = (l >= 1) ? x[(l - 1) * 300 + i] : 0.f;
    float x2 = (l <= 30) ? x[(l + 1) * 300 + i] : 0.f;
    acc += Wo[i * 3] * x0 + Wo[i * 3 + 1] * x1 + Wo[i * 3 + 2] * x2;
  }
  y[l * 300 + o] = leaky(acc) + x[l * 300 + o];
}

// ---------------- q_weights softmax + normalized qn / qcn ----------------
__global__ __launch_bounds__(256) void qfinish_kernel(
    const float* __restrict__ qemb, const float* __restrict__ qctx,
    const float* __restrict__ qidf, const float* __restrict__ qww,
    const float* __restrict__ qwb,
    float* __restrict__ qn, float* __restrict__ qcn, float* __restrict__ qwv)
{
  __shared__ float nq[32], nqc[32], lg[32];
  int tid = threadIdx.x, lane = tid & 63, w = tid >> 6;
  int r = w * 8 + (lane >> 3), sub = lane & 7;
  float sq = 0.f, sqc = 0.f, dt = 0.f;
  for (int i = sub; i < 300; i += 8) {
    float a = qemb[r * 300 + i]; sq  += a * a;
    float c = qctx[r * 300 + i]; sqc += c * c;
    dt += c * qww[i];
  }
#pragma unroll
  for (int off = 4; off; off >>= 1) {
    sq  += __shfl_xor(sq, off);
    sqc += __shfl_xor(sqc, off);
    dt  += __shfl_xor(dt, off);
  }
  if (sub == 0) {
    nq[r] = sq; nqc[r] = sqc;
    lg[r] = dt + qidf[r] * qww[300] + qwb[0];
  }
  __syncthreads();
  if (w == 0) {
    float L = (lane < 32) ? lg[lane] : -1e30f;
    float m = L;
#pragma unroll
    for (int off = 32; off; off >>= 1) m = fmaxf(m, __shfl_xor(m, off));
    float e = (lane < 32) ? expf(L - m) : 0.f;
    float ssum = e;
#pragma unroll
    for (int off = 32; off; off >>= 1) ssum += __shfl_xor(ssum, off);
    if (lane < 32) qwv[lane] = e / ssum;
  }
  __syncthreads();
  for (int idx = tid; idx < 9600; idx += 256) {
    int rr = idx / 300;
    qn[idx]  = qemb[idx] / sqrtf(nq[rr]);
    qcn[idx] = qctx[idx] / sqrtf(nqc[rr]);
  }
}

// ---------------- qn/qcn -> bf16 A-fragment layout ----------------
// frag idx = ((s*2 + mt)*10 + kt)*64 + lane ; element j: A[q=mt*16+(lane&15)][i=kt*32+(lane>>4)*8+j]
__global__ __launch_bounds__(256) void qfrag_kernel(
    const float* __restrict__ qn, const float* __restrict__ qcn,
    short* __restrict__ qf)
{
  int t = blockIdx.x * 256 + threadIdx.x;
  if (t >= 2560) return;
  int lane = t & 63;
  int rest = t >> 6;           // s*20 + mt*10 + kt
  int kt = rest % 10; rest /= 10;
  int mt = rest & 1;  int s = rest >> 1;
  const float* src = s ? qcn : qn;
  int q  = mt * 16 + (lane & 15);
  int i0 = kt * 32 + (lane >> 4) * 8;
  short8 v;
#pragma unroll
  for (int j = 0; j < 8; ++j) {
    int i = i0 + j;
    v[j] = f2b((i < 300) ? src[q * 300 + i] : 0.f);
  }
  *(short8*)(qf + (size_t)t * 8) = v;
}

// ---------------- W (300,300,3) fp32 -> bf16 A-fragment layout ----------------
// frag idx = ((tap*10 + kt)*20 + mt)*64 + lane ; element j: A_tap[o=mt*16+(lane&15)][i=kt*32+(lane>>4)*8+j]
__global__ __launch_bounds__(256) void wfrag_kernel(
    const float* __restrict__ W, short* __restrict__ Wf)
{
  int t = blockIdx.x * 256 + threadIdx.x;
  if (t >= 38400) return;
  int lane = t & 63;
  int rest = t >> 6;           // tap*200 + kt*20 + mt
  int mt = rest % 20; rest /= 20;
  int kt = rest % 10; int tap = rest / 10;
  int o  = mt * 16 + (lane & 15);
  int i0 = kt * 32 + (lane >> 4) * 8;
  short8 v;
#pragma unroll
  for (int j = 0; j < 8; ++j) {
    int i = i0 + j;
    v[j] = f2b((o < 300 && i < 300) ? W[o * 900 + i * 3 + tap] : 0.f);
  }
  *(short8*)(Wf + (size_t)t * 8) = v;
}

// ---------------- fused per-sentence kernel ----------------
__device__ __forceinline__ void norms_phase(const short* XT, float* invn, int tid) {
  int row = tid >> 3, part = tid & 7;
  const short* rp = XT + (row + 1) * XSTRIDE + part * 40;
  float ssum = 0.f;
#pragma unroll
  for (int u = 0; u < 5; ++u) {
    short8 hv = *(const short8*)(rp + u * 8);
#pragma unroll
    for (int j = 0; j < 8; ++j) { float f = b2f(hv[j]); ssum += f * f; }
  }
  ssum += __shfl_xor(ssum, 1);
  ssum += __shfl_xor(ssum, 2);
  ssum += __shfl_xor(ssum, 4);
  if ((tid & 7) == 0) invn[row] = rsqrtf(ssum);
}

// conv block: dst[o][l] = bf16( leaky(GEMM + b[o]) + src[o][l] ), GEMM over 3 taps x K=320
__device__ __forceinline__ void conv_mfma(
    const short* src, short* dst, const short* __restrict__ Wf,
    const float* __restrict__ bias, int w, int lane)
{
  int r = lane & 15, g = lane >> 4;
  int nmt = (w < 4) ? 3 : 2;          // wave w owns mtiles {w, w+8, w+16<20}
  f32x4 acc[3][4];
#pragma unroll
  for (int mi = 0; mi < 3; ++mi)
#pragma unroll
    for (int nt = 0; nt < 4; ++nt) acc[mi][nt] = (f32x4){0.f, 0.f, 0.f, 0.f};

  for (int kt = 0; kt < 10; ++kt) {
#pragma unroll
    for (int tap = 0; tap < 3; ++tap) {
      short8 bf[4];
#pragma unroll
      for (int nt = 0; nt < 4; ++nt)
        bf[nt] = *(const short8*)(src + (nt * 16 + r + tap) * XSTRIDE + kt * 32 + g * 8);
      const short* wp = Wf + (size_t)(((tap * 10 + kt) * 20) * 64 + lane) * 8;
#pragma unroll
      for (int mi = 0; mi < 3; ++mi) {
        if (mi < nmt) {
          int mt = w + 8 * mi;
          short8 af = *(const short8*)(wp + (size_t)mt * 64 * 8);
#pragma unroll
          for (int nt = 0; nt < 4; ++nt)
            acc[mi][nt] = __builtin_amdgcn_mfma_f32_16x16x32_bf16(af, bf[nt], acc[mi][nt], 0, 0, 0);
        }
      }
    }
  }
  // epilogue: bias + leaky + residual(bf16 src) -> dst
#pragma unroll
  for (int mi = 0; mi < 3; ++mi) {
    if (mi < nmt) {
      int mt = w + 8 * mi;
      int m0 = mt * 16 + g * 4;
      if (m0 < 300) {
        f32x4 bv = *(const f32x4*)(bias + m0);   // m0 <= 296
#pragma unroll
        for (int nt = 0; nt < 4; ++nt) {
          int l = nt * 16 + r;
          short4_t resv = *(const short4_t*)(src + (l + 1) * XSTRIDE + m0);
          short4_t outv;
#pragma unroll
          for (int j = 0; j < 4; ++j) {
            float a = acc[mi][nt][j] + bv[j];
            a = leaky(a) + b2f(resv[j]);
            outv[j] = f2b(a);
          }
          *(short4_t*)(dst + (l + 1) * XSTRIDE + m0) = outv;
        }
      }
    }
  }
}

// sim GEMM: SIM[q][l] = (A(32x300) . X[:,l]) * invn[l]; wave w -> tile (mt=w>>2, nt=w&3)
__device__ __forceinline__ void sim_mfma(
    const short* src, const short* __restrict__ qf,
    const float* invn, float* SIMb, int w, int lane)
{
  int r = lane & 15, g = lane >> 4;
  int mt = w >> 2, nt = w & 3;
  f32x4 acc = (f32x4){0.f, 0.f, 0.f, 0.f};
  for (int kt = 0; kt < 10; ++kt) {
    short8 bf = *(const short8*)(src + (nt * 16 + r + 1) * XSTRIDE + kt * 32 + g * 8);
    short8 af = *(const short8*)(qf + (size_t)((mt * 10 + kt) * 64 + lane) * 8);
    acc = __builtin_amdgcn_mfma_f32_16x16x32_bf16(af, bf, acc, 0, 0, 0);
  }
  int l = nt * 16 + r;
  float iv = invn[l];
#pragma unroll
  for (int j = 0; j < 4; ++j) {
    int q = mt * 16 + g * 4 + j;
    SIMb[q * 66 + l] = acc[j] * iv;
  }
}

__device__ __forceinline__ void pool_phase(
    const float* SIMb, float* feat, int w, int lane, int foff, bool do_oh)
{
  for (int qi = 0; qi < 4; ++qi) {
    int q = w * 4 + qi;
    float sim = SIMb[q * 66 + lane];
    float ssum = waveSum(sim);
    float vv = sim, tmax = 0.f, t5 = 0.f;
#pragma unroll
    for (int it = 0; it < 5; ++it) {
      float m = waveMax(vv);
      if (it == 0) tmax = m;
      t5 += m;
      unsigned long long bb = __ballot(vv == m);
      if (lane == (int)__builtin_ctzll(bb)) vv = -3e38f;
    }
    if (do_oh) {
      int c = __popcll(__ballot(sim > EPS_OH));
      if (lane == 0) {
        feat[q * 9 + 0] = (c > 0) ? 1.f : 0.f;
        feat[q * 9 + 1] = (c < 5 ? (float)c : 5.f) * 0.2f;
        feat[q * 9 + 2] = (float)c * (1.f / 64.f);
      }
    }
    if (lane == 0) {
      feat[q * 9 + foff + 0] = tmax;
      feat[q * 9 + foff + 1] = t5 * 0.2f;
      feat[q * 9 + foff + 2] = ssum * (1.f / 64.f);
    }
  }
}

__global__ __launch_bounds__(512) void sent_kernel(
    const float* __restrict__ doc, const short* __restrict__ qf,
    const float* __restrict__ qwv, const float* __restrict__ gaf,
    const short* __restrict__ Wf1, const float* __restrict__ b1,
    const short* __restrict__ Wf2, const float* __restrict__ b2,
    const float* __restrict__ m1w, const float* __restrict__ m1b,
    const float* __restrict__ m2w, const float* __restrict__ m2b,
    const float* __restrict__ ow, float* __restrict__ out)
{
  __shared__ short XT[NROWS * XSTRIDE + 16];
  __shared__ short YT[NROWS * XSTRIDE + 16];
  __shared__ float SIMb[32 * 66];
  __shared__ float invn[64];
  __shared__ float feat[32 * 9];

  int tid = threadIdx.x, lane = tid & 63, w = tid >> 6;
  int s = blockIdx.x;

  // P0: zero both LDS tile buffers (pads included)
  for (int idx = tid * 8; idx < NROWS * XSTRIDE + 16; idx += 512 * 8) {
    *(short8*)(XT + idx) = (short8)0;
    *(short8*)(YT + idx) = (short8)0;
  }
  __syncthreads();

  // P1: load x (l,i) fp32 -> XT[l+1][i] bf16 (transpose to channel-contiguous rows)
  {
    int l = tid >> 3, part = tid & 7;
    const float* xr = doc + (size_t)s * 19200 + l * 300;
#pragma unroll
    for (int m = 0; m < 5; ++m) {
      int c = part * 8 + m * 64;
      if (c < 300) {
        float v[8];
        if (c <= 292) {
          f32x4 u0 = *(const f32x4*)(xr + c);
          f32x4 u1 = *(const f32x4*)(xr + c + 4);
#pragma unroll
          for (int j = 0; j < 4; ++j) { v[j] = u0[j]; v[4 + j] = u1[j]; }
        } else {
#pragma unroll
          for (int j = 0; j < 8; ++j) v[j] = (c + j < 300) ? xr[c + j] : 0.f;
        }
        short8 o;
#pragma unroll
        for (int j = 0; j < 8; ++j) o[j] = f2b(v[j]);
        *(short8*)(XT + (l + 1) * XSTRIDE + c) = o;
      }
    }
  }
  __syncthreads();

  // P2: row norms of x
  norms_phase(XT, invn, tid);
  __syncthreads();

  // P3: sim_insens GEMM -> SIM
  sim_mfma(XT, qf, invn, SIMb, w, lane);
  __syncthreads();

  // P4: pool oh + insens
  pool_phase(SIMb, feat, w, lane, 3, true);
  __syncthreads();

  // P5: conv1 XT -> YT
  conv_mfma(XT, YT, Wf1, b1, w, lane);
  __syncthreads();

  // P6: conv2 YT -> XT
  conv_mfma(YT, XT, Wf2, b2, w, lane);
  __syncthreads();

  // P7: row norms of sent_ctx
  norms_phase(XT, invn, tid);
  __syncthreads();

  // P8: sim_sens GEMM (qcn frags at +10240)
  sim_mfma(XT, qf + 10240, invn, SIMb, w, lane);
  __syncthreads();

  // P9: pool sens
  pool_phase(SIMb, feat, w, lane, 6, false);
  __syncthreads();

  // P10: MLP + weighted emit + sigmoid (wave 0)
  if (w == 0) {
    float val = 0.f;
    if (lane < 32) {
      int q = lane;
      float o8 = m2b[0];
#pragma unroll
      for (int j = 0; j < 8; ++j) {
        float a = m1b[j];
#pragma unroll
        for (int f = 0; f < 9; ++f) a += m1w[j * 9 + f] * feat[q * 9 + f];
        a = leaky(a);
        o8 += m2w[j] * a;
      }
      val = o8 * qwv[q];
    }
    float tot = waveSum(val);
    if (lane == 0) {
      float emit = tot * (1.f / 32.f);
      float z = gaf[s * 3 + 0] * ow[0] + gaf[s * 3 + 1] * ow[1] +
                gaf[s * 3 + 2] * ow[2] + emit * ow[3];
      out[s] = 1.f / (1.f + expf(-z));
    }
  }
}

extern "C" void kernel_launch(void* const* d_in, const int* in_sizes, int n_in,
                              void* d_out, int out_size, void* d_ws, size_t ws_size,
                              hipStream_t stream)
{
  const float* doc  = (const float*)d_in[0];
  const float* qemb = (const float*)d_in[1];
  const float* qidf = (const float*)d_in[2];
  const float* gaf  = (const float*)d_in[3];
  const float* W1   = (const float*)d_in[4];
  const float* b1   = (const float*)d_in[5];
  const float* W2   = (const float*)d_in[6];
  const float* b2   = (const float*)d_in[7];
  const float* qww  = (const float*)d_in[8];
  const float* qwb  = (const float*)d_in[9];
  const float* m1w  = (const float*)d_in[10];
  const float* m1b  = (const float*)d_in[11];
  const float* m2w  = (const float*)d_in[12];
  const float* m2b  = (const float*)d_in[13];
  const float* ow   = (const float*)d_in[14];
  float* out = (float*)d_out;

  float* ws   = (float*)d_ws;
  float* qc1  = ws;             // 9600 f32
  float* qctx = ws + 9600;      // 9600
  float* qn   = ws + 19200;     // 9600
  float* qcn  = ws + 28800;     // 9600
  float* qwv  = ws + 38400;     // 32
  short* wsS  = (short*)(ws + 38432);   // 16B-aligned
  short* Wf1  = wsS;                    // 307200 bf16
  short* Wf2  = wsS + 307200;           // 307200 bf16
  short* qfS  = wsS + 614400;           // 20480 bf16
  // total ws: ~1.36 MB

  qconv_kernel<<<38, 256, 0, stream>>>(qemb, W1, b1, qc1);
  qconv_kernel<<<38, 256, 0, stream>>>(qc1, W2, b2, qctx);
  qfinish_kernel<<<1, 256, 0, stream>>>(qemb, qctx, qidf, qww, qwb, qn, qcn, qwv);
  qfrag_kernel<<<10, 256, 0, stream>>>(qn, qcn, qfS);
  wfrag_kernel<<<150, 256, 0, stream>>>(W1, Wf1);
  wfrag_kernel<<<150, 256, 0, stream>>>(W2, Wf2);
  sent_kernel<<<4096, 512, 0, stream>>>(doc, qfS, qwv, gaf, Wf1, b1, Wf2, b2,
                                        m1w, m1b, m2w, m2b, ow, out);
}

// Round 3
// 644.053 us; speedup vs baseline: 36.1713x; 1.2847x over previous
//
#include <hip/hip_runtime.h>
#include <math.h>

typedef __attribute__((ext_vector_type(8))) short short8;
typedef __attribute__((ext_vector_type(4))) short short4_t;
typedef __attribute__((ext_vector_type(4))) float f32x4;

#define RS      312          // shorts per LDS tile row (624 B = 39*16B, 39%8=7 -> conflict-free b128)
#define EPS_OH  0.999f

__device__ __forceinline__ float waveSum(float v) {
#pragma unroll
  for (int off = 32; off; off >>= 1) v += __shfl_xor(v, off);
  return v;
}
__device__ __forceinline__ float waveMax(float v) {
#pragma unroll
  for (int off = 32; off; off >>= 1) v = fmaxf(v, __shfl_xor(v, off));
  return v;
}
__device__ __forceinline__ float leaky(float x) { return fmaxf(x, 0.1f * x); }

__device__ __forceinline__ short f2b(float f) {
  unsigned u = __float_as_uint(f);
  unsigned r = (u + 0x7FFFu + ((u >> 16) & 1u)) >> 16;
  return (short)r;
}
__device__ __forceinline__ float b2f(short h) {
  return __uint_as_float(((unsigned)(unsigned short)h) << 16);
}

// ---------------- question-side conv block (fp32, tiny), 8 lanes per output ----------------
__global__ __launch_bounds__(256) void qconv_kernel(
    const float* __restrict__ x, const float* __restrict__ W,
    const float* __restrict__ b, float* __restrict__ y)
{
  int idx = blockIdx.x * 256 + threadIdx.x;      // (l*300+o)*8 + part
  if (idx >= 76800) return;
  int part = idx & 7, gid = idx >> 3;
  int o = gid % 300, l = gid / 300;
  const float* Wo = W + o * 900;
  float acc = 0.f;
  for (int i = part; i < 300; i += 8) {
    float x1 = x[l * 300 + i];
    float x0 = (l >= 1) ? x[(l - 1) * 300 + i] : 0.f;
    float x2 = (l <= 30) ? x[(l + 1) * 300 + i] : 0.f;
    acc += Wo[i * 3] * x0 + Wo[i * 3 + 1] * x1 + Wo[i * 3 + 2] * x2;
  }
  acc += __shfl_xor(acc, 1);
  acc += __shfl_xor(acc, 2);
  acc += __shfl_xor(acc, 4);
  if (part == 0) y[gid] = leaky(acc + b[o]) + x[gid];
}

// ---------------- q_weights softmax + normalized q fragments (bf16 A-layout) ----------------
// frag idx = ((s*2+mt)*10+kt)*64 + lane ; elem j: A[q=mt*16+(lane&15)][i=kt*32+(lane>>4)*8+j]
__global__ __launch_bounds__(256) void qfinish_kernel(
    const float* __restrict__ qemb, const float* __restrict__ qctx,
    const float* __restrict__ qidf, const float* __restrict__ qww,
    const float* __restrict__ qwb,
    float* __restrict__ qwv, short* __restrict__ qf)
{
  __shared__ float inq[32], inqc[32], lg[32];
  int tid = threadIdx.x, lane = tid & 63, w = tid >> 6;
  int r = w * 8 + (lane >> 3), sub = lane & 7;
  float sq = 0.f, sqc = 0.f, dt = 0.f;
  for (int i = sub; i < 300; i += 8) {
    float a = qemb[r * 300 + i]; sq  += a * a;
    float c = qctx[r * 300 + i]; sqc += c * c;
    dt += c * qww[i];
  }
#pragma unroll
  for (int off = 4; off; off >>= 1) {
    sq  += __shfl_xor(sq, off);
    sqc += __shfl_xor(sqc, off);
    dt  += __shfl_xor(dt, off);
  }
  if (sub == 0) {
    inq[r] = rsqrtf(sq); inqc[r] = rsqrtf(sqc);
    lg[r] = dt + qidf[r] * qww[300] + qwb[0];
  }
  __syncthreads();
  if (w == 0) {
    float L = (lane < 32) ? lg[lane] : -1e30f;
    float m = L;
#pragma unroll
    for (int off = 32; off; off >>= 1) m = fmaxf(m, __shfl_xor(m, off));
    float e = (lane < 32) ? expf(L - m) : 0.f;
    float ssum = e;
#pragma unroll
    for (int off = 32; off; off >>= 1) ssum += __shfl_xor(ssum, off);
    if (lane < 32) qwv[lane] = e / ssum;
  }
  __syncthreads();
  for (int t = tid; t < 2560; t += 256) {
    int ln = t & 63;
    int rest = t >> 6;
    int kt = rest % 10; rest /= 10;
    int mt = rest & 1; int sflag = rest >> 1;
    const float* src  = sflag ? qctx : qemb;
    const float* innv = sflag ? inqc : inq;
    int q  = mt * 16 + (ln & 15);
    int i0 = kt * 32 + (ln >> 4) * 8;
    float iv = innv[q];
    short8 v;
#pragma unroll
    for (int j = 0; j < 8; ++j) {
      int i = i0 + j;
      v[j] = f2b((i < 300) ? src[q * 300 + i] * iv : 0.f);
    }
    *(short8*)(qf + (size_t)t * 8) = v;
  }
}

// ---------------- W (300,300,3) fp32 -> bf16 A-fragment layout ----------------
// frag idx = ((tap*10+kt)*20 + mt)*64 + lane ; elem j: A_tap[o=mt*16+(lane&15)][i=kt*32+(lane>>4)*8+j]
__global__ __launch_bounds__(256) void wfrag_kernel(
    const float* __restrict__ W, short* __restrict__ Wf)
{
  int t = blockIdx.x * 256 + threadIdx.x;
  if (t >= 38400) return;
  int lane = t & 63;
  int rest = t >> 6;
  int mt = rest % 20; rest /= 20;
  int kt = rest % 10; int tap = rest / 10;
  int o  = mt * 16 + (lane & 15);
  int i0 = kt * 32 + (lane >> 4) * 8;
  short8 v;
#pragma unroll
  for (int j = 0; j < 8; ++j) {
    int i = i0 + j;
    v[j] = f2b((o < 300 && i < 300) ? W[o * 900 + i * 3 + tap] : 0.f);
  }
  *(short8*)(Wf + (size_t)t * 8) = v;
}

// ---------------- fused per-sentence kernel helpers ----------------

// conv block: dst[o][l] = bf16( leaky(GEMM+b[o]) + src[o][l] ); GEMM over 3 taps x K=320
__device__ __forceinline__ void conv_mfma(
    const short* src, short* dst, const short* __restrict__ Wf,
    const float* __restrict__ bias, int w, int lane)
{
  const int r = lane & 15, g = lane >> 4;
  const int nmt = (w < 3) ? 3 : 2;      // mt=19 (all-zero pad tile) skipped
  f32x4 acc[3][4];
#pragma unroll
  for (int mi = 0; mi < 3; ++mi)
#pragma unroll
    for (int nt = 0; nt < 4; ++nt) acc[mi][nt] = (f32x4){0.f, 0.f, 0.f, 0.f};

#pragma unroll 2
  for (int kt = 0; kt < 10; ++kt) {
#pragma unroll
    for (int tap = 0; tap < 3; ++tap) {
      short8 bf[4];
#pragma unroll
      for (int nt = 0; nt < 4; ++nt) {
        int rowi = nt * 16 + r + tap - 1;
        if (tap == 0 && nt == 0) rowi = (rowi < 0) ? 0 : rowi;     // clamp, masked below
        if (tap == 2 && nt == 3) rowi = (rowi > 63) ? 63 : rowi;   // clamp, masked below
        bf[nt] = *(const short8*)(src + rowi * RS + kt * 32 + g * 8);
      }
      if (tap == 0) bf[0] = (r == 0)  ? (short8)0 : bf[0];   // position -1 -> 0
      if (tap == 2) bf[3] = (r == 15) ? (short8)0 : bf[3];   // position 64 -> 0
      const short* wp = Wf + (size_t)(((tap * 10 + kt) * 20) * 64 + lane) * 8;
#pragma unroll
      for (int mi = 0; mi < 3; ++mi) {
        if (mi < nmt) {
          int mt = w + 8 * mi;
          short8 af = *(const short8*)(wp + (size_t)mt * 512);
#pragma unroll
          for (int nt = 0; nt < 4; ++nt)
            acc[mi][nt] = __builtin_amdgcn_mfma_f32_16x16x32_bf16(af, bf[nt], acc[mi][nt], 0, 0, 0);
        }
      }
    }
  }
#pragma unroll
  for (int mi = 0; mi < 3; ++mi) {
    if (mi < nmt) {
      int mt = w + 8 * mi;
      int m0 = mt * 16 + g * 4;
      if (m0 < 300) {
        f32x4 bv = *(const f32x4*)(bias + m0);
#pragma unroll
        for (int nt = 0; nt < 4; ++nt) {
          int l = nt * 16 + r;
          short4_t resv = *(const short4_t*)(src + l * RS + m0);
          short4_t outv;
#pragma unroll
          for (int j = 0; j < 4; ++j) {
            float a = acc[mi][nt][j] + bv[j];
            a = leaky(a) + b2f(resv[j]);
            outv[j] = f2b(a);
          }
          *(short4_t*)(dst + l * RS + m0) = outv;
        }
      }
    }
  }
}

// sim GEMM: SIMb[q][l] = A(32x300,normalized q) . src[:,l]  (unscaled; invn applied in pool)
__device__ __forceinline__ void sim_mfma(
    const short* src, const short* __restrict__ qf, float* SIMb, int w, int lane)
{
  int r = lane & 15, g = lane >> 4;
  int mt = w >> 2, nt = w & 3;
  f32x4 acc = (f32x4){0.f, 0.f, 0.f, 0.f};
#pragma unroll
  for (int kt = 0; kt < 10; ++kt) {
    short8 bf = *(const short8*)(src + (nt * 16 + r) * RS + kt * 32 + g * 8);
    short8 af = *(const short8*)(qf + (size_t)((mt * 10 + kt) * 64 + lane) * 8);
    acc = __builtin_amdgcn_mfma_f32_16x16x32_bf16(af, bf, acc, 0, 0, 0);
  }
  int l = nt * 16 + r;
#pragma unroll
  for (int j = 0; j < 4; ++j)
    SIMb[(mt * 16 + g * 4 + j) * 68 + l] = acc[j];
}

// pooling for 4 q's per wave; results kept in registers (static indices)
__device__ __forceinline__ void pool3(
    const float* SIMb, const float* invn, int w, int lane,
    float* st, float* ohst)
{
#pragma unroll
  for (int qi = 0; qi < 4; ++qi) {
    int q = w * 4 + qi;
    float sim = SIMb[q * 68 + lane] * invn[lane];
    float ssum = waveSum(sim);
    float vv = sim, tmax = 0.f, t5 = 0.f;
#pragma unroll
    for (int it = 0; it < 5; ++it) {
      float m = waveMax(vv);
      if (it == 0) tmax = m;
      t5 += m;
      unsigned long long bb = __ballot(vv == m);
      if (lane == (int)__builtin_ctzll(bb)) vv = -3e38f;
    }
    if (ohst) {
      int c = __popcll(__ballot(sim > EPS_OH));
      ohst[qi * 3 + 0] = (c > 0) ? 1.f : 0.f;
      ohst[qi * 3 + 1] = (c < 5 ? (float)c : 5.f) * 0.2f;
      ohst[qi * 3 + 2] = (float)c * (1.f / 64.f);
    }
    st[qi * 3 + 0] = tmax;
    st[qi * 3 + 1] = t5 * 0.2f;
    st[qi * 3 + 2] = ssum * (1.f / 64.f);
  }
}

__device__ __forceinline__ void norms_lds(const short* Xb, float* invn, int tid) {
  int row = tid >> 3, part = tid & 7;
  float ssum = 0.f;
  for (int i = part * 8; i < 304; i += 64) {
    short8 hv = *(const short8*)(Xb + row * RS + i);
#pragma unroll
    for (int j = 0; j < 8; ++j) { float f = b2f(hv[j]); ssum += f * f; }
  }
  ssum += __shfl_xor(ssum, 1);
  ssum += __shfl_xor(ssum, 2);
  ssum += __shfl_xor(ssum, 4);
  if (part == 0) invn[row] = rsqrtf(ssum);
}

__global__ __launch_bounds__(512, 4) void sent_kernel(
    const float* __restrict__ doc, const short* __restrict__ qf,
    const float* __restrict__ qwv, const float* __restrict__ gaf,
    const short* __restrict__ Wf1, const float* __restrict__ b1,
    const short* __restrict__ Wf2, const float* __restrict__ b2,
    const float* __restrict__ m1w, const float* __restrict__ m1b,
    const float* __restrict__ m2w, const float* __restrict__ m2b,
    const float* __restrict__ ow, float* __restrict__ out)
{
  __shared__ short TB[128 * RS + 8];   // X body rows 0..63, Y body rows 64..127, 8-short end pad
  __shared__ float invn[64];
  __shared__ float featb[32 * 9];
  float* SIMb = (float*)(TB + 65 * RS);   // overlay on Y rows 1..14 (dead during sim/pool)

  const int tid = threadIdx.x, lane = tid & 63, w = tid >> 6;
  const int s = blockIdx.x;
  short* Xb = TB;
  short* Yb = TB + 64 * RS;

  // ---- Phase A: zero pads (disjoint bytes) + load+convert + inline fp32 norms ----
  if (tid < 128) {                       // cols 300..311 of every row
    short* p = TB + tid * RS + 300;
    *(short4_t*)p = (short4_t)0;
    *(short8*)(p + 4) = (short8)0;
  } else if (tid == 128) {               // Y row 0 cols 0..7 (sim/conv1 edge reads)
    *(short8*)(Yb) = (short8)0;
  } else if (tid == 129) {               // end pad (conv2 edge reads)
    *(short8*)(TB + 128 * RS) = (short8)0;
  }
  {
    int l = tid >> 3, part = tid & 7;
    const float* xr = doc + (size_t)s * 19200 + l * 300;
    float ssum = 0.f;
#pragma unroll
    for (int m = 0; m < 5; ++m) {
      int c = part * 8 + m * 64;
      if (c <= 292) {
        f32x4 u0 = *(const f32x4*)(xr + c);
        f32x4 u1 = *(const f32x4*)(xr + c + 4);
        short8 o;
#pragma unroll
        for (int j = 0; j < 4; ++j) {
          ssum += u0[j] * u0[j] + u1[j] * u1[j];
          o[j] = f2b(u0[j]); o[4 + j] = f2b(u1[j]);
        }
        *(short8*)(Xb + l * RS + c) = o;
      } else if (c == 296) {
        f32x4 u0 = *(const f32x4*)(xr + 296);
        short4_t o;
#pragma unroll
        for (int j = 0; j < 4; ++j) { ssum += u0[j] * u0[j]; o[j] = f2b(u0[j]); }
        *(short4_t*)(Xb + l * RS + 296) = o;
      }
    }
    ssum += __shfl_xor(ssum, 1);
    ssum += __shfl_xor(ssum, 2);
    ssum += __shfl_xor(ssum, 4);
    if (part == 0) invn[l] = rsqrtf(ssum);
  }
  __syncthreads();

  // ---- Phase B: sim_insens GEMM ----
  sim_mfma(Xb, qf, SIMb, w, lane);
  __syncthreads();

  // ---- Phase C: pool oh + insens -> registers ----
  float oh_st[12], ins_st[12], sens_st[12];
  pool3(SIMb, invn, w, lane, ins_st, oh_st);
  __syncthreads();

  // ---- Phase D: re-zero SIMb-contaminated pad cols (disjoint from conv1) + conv1 X->Y ----
  if (tid < 17) {
    short* p = Yb + (1 + tid) * RS + 300;
    *(short4_t*)p = (short4_t)0;
    *(short8*)(p + 4) = (short8)0;
  }
  conv_mfma(Xb, Yb, Wf1, b1, w, lane);
  __syncthreads();

  // ---- Phase E: conv2 Y->X ----
  conv_mfma(Yb, Xb, Wf2, b2, w, lane);
  __syncthreads();

  // ---- Phase F: ctx norms + sim_sens GEMM ----
  norms_lds(Xb, invn, tid);
  sim_mfma(Xb, qf + 10240, SIMb, w, lane);
  __syncthreads();

  // ---- Phase G: pool sens + write all feats ----
  pool3(SIMb, invn, w, lane, sens_st, (float*)0);
  if (lane == 0) {
#pragma unroll
    for (int qi = 0; qi < 4; ++qi) {
      int q = w * 4 + qi;
#pragma unroll
      for (int k = 0; k < 3; ++k) {
        featb[q * 9 + k]     = oh_st[qi * 3 + k];
        featb[q * 9 + 3 + k] = ins_st[qi * 3 + k];
        featb[q * 9 + 6 + k] = sens_st[qi * 3 + k];
      }
    }
  }
  __syncthreads();

  // ---- Phase H: MLP + weighted emit + sigmoid (wave 0) ----
  if (w == 0) {
    float val = 0.f;
    if (lane < 32) {
      int q = lane;
      float o8 = m2b[0];
#pragma unroll
      for (int j = 0; j < 8; ++j) {
        float a = m1b[j];
#pragma unroll
        for (int f = 0; f < 9; ++f) a += m1w[j * 9 + f] * featb[q * 9 + f];
        a = leaky(a);
        o8 += m2w[j] * a;
      }
      val = o8 * qwv[q];
    }
    float tot = waveSum(val);
    if (lane == 0) {
      float emit = tot * (1.f / 32.f);
      float z = gaf[s * 3 + 0] * ow[0] + gaf[s * 3 + 1] * ow[1] +
                gaf[s * 3 + 2] * ow[2] + emit * ow[3];
      out[s] = 1.f / (1.f + expf(-z));
    }
  }
}

extern "C" void kernel_launch(void* const* d_in, const int* in_sizes, int n_in,
                              void* d_out, int out_size, void* d_ws, size_t ws_size,
                              hipStream_t stream)
{
  const float* doc  = (const float*)d_in[0];
  const float* qemb = (const float*)d_in[1];
  const float* qidf = (const float*)d_in[2];
  const float* gaf  = (const float*)d_in[3];
  const float* W1   = (const float*)d_in[4];
  const float* b1   = (const float*)d_in[5];
  const float* W2   = (const float*)d_in[6];
  const float* b2   = (const float*)d_in[7];
  const float* qww  = (const float*)d_in[8];
  const float* qwb  = (const float*)d_in[9];
  const float* m1w  = (const float*)d_in[10];
  const float* m1b  = (const float*)d_in[11];
  const float* m2w  = (const float*)d_in[12];
  const float* m2b  = (const float*)d_in[13];
  const float* ow   = (const float*)d_in[14];
  float* out = (float*)d_out;

  float* ws   = (float*)d_ws;
  float* qc1  = ws;                     // 9600 f32
  float* qctx = ws + 9600;              // 9600 f32
  float* qwv  = ws + 19200;             // 32 f32
  short* wsS  = (short*)(ws + 19232);   // 16B-aligned
  short* Wf1  = wsS;                    // 307200 bf16
  short* Wf2  = wsS + 307200;           // 307200 bf16
  short* qfS  = wsS + 614400;           // 20480 bf16

  wfrag_kernel<<<150, 256, 0, stream>>>(W1, Wf1);
  wfrag_kernel<<<150, 256, 0, stream>>>(W2, Wf2);
  qconv_kernel<<<300, 256, 0, stream>>>(qemb, W1, b1, qc1);
  qconv_kernel<<<300, 256, 0, stream>>>(qc1, W2, b2, qctx);
  qfinish_kernel<<<1, 256, 0, stream>>>(qemb, qctx, qidf, qww, qwb, qwv, qfS);
  sent_kernel<<<4096, 512, 0, stream>>>(doc, qfS, qwv, gaf, Wf1, b1, Wf2, b2,
                                        m1w, m1b, m2w, m2b, ow, out);
}